// Round 6
// baseline (489.039 us; speedup 1.0000x reference)
//
#include <hip/hip_runtime.h>
#include <hip/hip_fp16.h>

typedef _Float16 f16x8 __attribute__((ext_vector_type(8)));
typedef float f32x4 __attribute__((ext_vector_type(4)));

#define KSEL0 1372u   // int(2048*0.67)
#define KSEL1 1536u   // int(2048*0.75)
#define KSEL2 1638u   // int(2048*0.80)
#define WSC 16.0f

__device__ __forceinline__ unsigned ou16_of(unsigned hb) {
  return hb ^ ((hb & 0x8000u) ? 0xFFFFu : 0x8000u);
}
__device__ __forceinline__ unsigned ou16_inv(unsigned ou) {
  return (ou & 0x8000u) ? (ou ^ 0x8000u) : (ou ^ 0xFFFFu);
}
__device__ __forceinline__ unsigned pk2(float a, float b) {
  auto h = __builtin_amdgcn_cvt_pkrtz(a, b);
  return __builtin_bit_cast(unsigned, h);
}
__device__ __forceinline__ unsigned shflx(unsigned v, int m) {
  return (unsigned)__shfl_xor((int)v, m, 64);
}

// inclusive suffix-sum over 64 lanes
__device__ __forceinline__ unsigned suffix64(unsigned s4, int lane) {
  unsigned p = s4;
  #pragma unroll
  for (int off = 1; off < 64; off <<= 1) {
    int sl = lane + off;
    unsigned t = (unsigned)__shfl((int)p, sl < 64 ? sl : lane, 64);
    p += (sl < 64) ? t : 0u;
  }
  return p;
}
// given per-lane bin counts (bins 4l..4l+3) and suffix tail, pick digit for k-th largest
__device__ __forceinline__ unsigned pick_digit(unsigned tail, unsigned hx, unsigned hy,
                                               unsigned hz, unsigned hw_, unsigned k, int lane) {
  unsigned s4 = hx + hy + hz + hw_;
  unsigned a3 = tail - s4;
  unsigned a2 = a3 + hw_;
  unsigned a1 = a2 + hz;
  unsigned a0 = a1 + hy;
  int d = -1; unsigned nk = 0;
  if (a3 < k && a3 + hw_ >= k)      { d = 4*lane+3; nk = k - a3; }
  else if (a2 < k && a2 + hz >= k)  { d = 4*lane+2; nk = k - a2; }
  else if (a1 < k && a1 + hy >= k)  { d = 4*lane+1; nk = k - a1; }
  else if (a0 < k && a0 + hx >= k)  { d = 4*lane+0; nk = k - a0; }
  unsigned long long mb = __ballot(d >= 0);
  int src = __ffsll(mb) - 1;
  unsigned pack = ((unsigned)d << 16) | nk;
  return (unsigned)__shfl((int)pack, src, 64);
}

// ---------- prep: K fp32 -> Kh fp16 [bh][s][e] ----------
extern "C" __global__ __launch_bounds__(256)
void prep_k(const float* __restrict__ K, unsigned short* __restrict__ Kh) {
  int idx = blockIdx.x * 256 + threadIdx.x;
  int ec = idx & 7;
  int s  = (idx >> 3) & 2047;
  int bh = idx >> 14;
  int b = bh >> 3, h = bh & 7;
  const float* src = K + (((size_t)b * 2048 + s) * 8 + h) * 64 + ec * 8;
  float4 a = *(const float4*)src;
  float4 c = *(const float4*)(src + 4);
  uint4 val = { pk2(a.x, a.y), pk2(a.z, a.w), pk2(c.x, c.y), pk2(c.z, c.w) };
  *(uint4*)(Kh + (size_t)idx * 8) = val;
}

// ---------- prep: V fp32 -> Vt fp16 [bh][d][s] (transposed) ----------
extern "C" __global__ __launch_bounds__(256)
void prep_v(const float* __restrict__ V, unsigned short* __restrict__ Vt) {
  const int tid  = threadIdx.x;
  const int w    = tid >> 6;
  const int lane = tid & 63;
  const int u_   = lane >> 4;
  const int dq   = (lane >> 2) & 3;
  const int r_   = lane & 3;
  const unsigned selv = (lane & 1) ? 0x03020706u : 0x05040100u;

  int bh = blockIdx.x >> 4;
  int s0 = (blockIdx.x & 15) * 128;
  int b = bh >> 3, h = bh & 7;
  const float* Vb = V + ((size_t)b * 2048 * 8 + h) * 64;
  unsigned short* Vo = Vt + (size_t)bh * 64 * 2048;

  #pragma unroll
  for (int sp = 0; sp < 2; ++sp) {
    #pragma unroll
    for (int p = 0; p < 4; ++p) {
      int sl = w * 32 + sp * 16 + u_ * 4;
      int sg = s0 + sl + r_;
      int d0 = p * 16 + dq * 4;
      float4 f = *(const float4*)(Vb + (size_t)sg * 512 + d0);
      unsigned lo = pk2(f.x, f.y), hi = pk2(f.z, f.w);
      unsigned tlo = shflx(lo, 1), thi = shflx(hi, 1);
      lo = __builtin_amdgcn_perm(tlo, lo, selv);
      hi = __builtin_amdgcn_perm(thi, hi, selv);
      unsigned t2lo = shflx(lo, 2), t2hi = shflx(hi, 2);
      unsigned Aw = (lane & 2) ? t2hi : lo;
      unsigned Bw = (lane & 2) ? hi   : t2lo;
      int d = d0 + r_;
      uint2 wv = {Aw, Bw};
      *(uint2*)(Vo + (size_t)d * 2048 + s0 + sl) = wv;
    }
  }
}

// ---------- main: 512 threads (8 waves), 16 q-rows, scores register-resident ----------
extern "C" __global__ __launch_bounds__(512, 4)
void nma_kernel(const float* __restrict__ Q, const unsigned short* __restrict__ Kh,
                const unsigned short* __restrict__ Vt, const float* __restrict__ AW,
                float* __restrict__ Out)
{
  // LDS [0,64K):  early = hist2 uint2[16][256] at [0,32K) + scratch [32K,36K)
  //               late  = weights w[16 rows][2048] fp16, row q swizzled ^(((q&7)<<4)|((q&8)<<3))
  // LDS [64K,80K): hist1 uint[16][256]; later PV partials (8KB)
  __shared__ __align__(16) char lds[81920];
  unsigned* hist1 = (unsigned*)(lds + 65536);
  unsigned* h2    = (unsigned*)lds;            // [row*512 + bin*2 (+1 for D2)]
  char* dkbuf = lds + 32768;                   // uint4 per row: digits, k0|k1, k2, m
  char* tmbuf = lds + 33024;                   // uint4 per row: T1o,T2o,T3o,0
  char* zbuf  = lds + 33280;                   // float4 z[16][8]

  const int tid  = threadIdx.x;
  const int w    = tid >> 6;      // wave 0..7
  const int lane = tid & 63;
  const int g    = lane >> 4;
  const int lx   = lane & 15;

  // XCD-aware bijective swizzle (4096 % 8 == 0)
  int bid = blockIdx.x;
  int lb  = (bid & 7) * 512 + (bid >> 3);
  int bh  = lb >> 7;
  int b   = bh >> 3, hh = bh & 7;
  int l0  = (lb & 127) << 4;

  const float* Qb = Q + (((size_t)b * 2048 + l0) * 8 + hh) * 64;
  const unsigned short* Khb = Kh + (size_t)bh * 2048 * 64;
  const unsigned short* Vtb = Vt + (size_t)bh * 64 * 2048;

  // zero hist1 (16KB) + hist2 (32KB)
  {
    uint4 z4 = {0u,0u,0u,0u};
    uint4* p1 = (uint4*)hist1;
    p1[tid] = z4; p1[tid + 512] = z4;
    uint4* p2 = (uint4*)lds;
    p2[tid] = z4; p2[tid + 512] = z4; p2[tid + 1024] = z4; p2[tid + 1536] = z4;
  }

  // Q B-frag (col=lx, k=g*8..), scale 1/8 folded
  union FU { f16x8 v; unsigned u[4]; };
  FU qa0, qa1;
  {
    const float* qp = Qb + (size_t)lx * 512 + g * 8;
    float4 a = *(const float4*)(qp);
    float4 c = *(const float4*)(qp + 4);
    qa0.u[0] = pk2(a.x*0.125f, a.y*0.125f); qa0.u[1] = pk2(a.z*0.125f, a.w*0.125f);
    qa0.u[2] = pk2(c.x*0.125f, c.y*0.125f); qa0.u[3] = pk2(c.z*0.125f, c.w*0.125f);
    a = *(const float4*)(qp + 32);
    c = *(const float4*)(qp + 36);
    qa1.u[0] = pk2(a.x*0.125f, a.y*0.125f); qa1.u[1] = pk2(a.z*0.125f, a.w*0.125f);
    qa1.u[2] = pk2(c.x*0.125f, c.y*0.125f); qa1.u[3] = pk2(c.z*0.125f, c.w*0.125f);
  }
  __syncthreads();

  // ===== QK^T transposed (D[s][q]): lane holds 4 consecutive s for row q=lx; scores stay in regs =====
  unsigned sreg[32];
  unsigned* hq = hist1 + lx * 256;
  #pragma unroll
  for (int t = 0; t < 16; ++t) {
    int s0 = (t * 8 + w) * 16;
    const unsigned short* kp = Khb + (size_t)(s0 + lx) * 64 + g * 8;
    f16x8 kb0 = *(const f16x8*)(kp);
    f16x8 kb1 = *(const f16x8*)(kp + 32);
    f32x4 acc = {0.f, 0.f, 0.f, 0.f};
    acc = __builtin_amdgcn_mfma_f32_16x16x32_f16(kb0, qa0.v, acc, 0, 0, 0);
    acc = __builtin_amdgcn_mfma_f32_16x16x32_f16(kb1, qa1.v, acc, 0, 0, 0);
    unsigned u0 = pk2(acc[0], acc[1]);
    unsigned u1 = pk2(acc[2], acc[3]);
    sreg[2*t]   = u0;
    sreg[2*t+1] = u1;
    atomicAdd(&hq[ou16_of(u0 & 0xFFFFu) >> 8], 1u);
    atomicAdd(&hq[ou16_of(u0 >> 16) >> 8], 1u);
    atomicAdd(&hq[ou16_of(u1 & 0xFFFFu) >> 8], 1u);
    atomicAdd(&hq[ou16_of(u1 >> 16) >> 8], 1u);
  }
  __syncthreads();

  const float aw0 = AW[0], aw1 = AW[1], aw2 = AW[2];

  // ===== round 1: wave w selects for rows 2w, 2w+1 (one shared suffix scan per row) =====
  #pragma unroll
  for (int rr = 0; rr < 2; ++rr) {
    int q = 2 * w + rr;
    uint4 hb = ((const uint4*)(hist1 + q * 256))[lane];
    unsigned tail = suffix64(hb.x + hb.y + hb.z + hb.w, lane);
    unsigned p0 = pick_digit(tail, hb.x, hb.y, hb.z, hb.w, KSEL0, lane);
    unsigned p1 = pick_digit(tail, hb.x, hb.y, hb.z, hb.w, KSEL1, lane);
    unsigned p2 = pick_digit(tail, hb.x, hb.y, hb.z, hb.w, KSEL2, lane);
    int md = hb.w ? lane*4+3 : hb.z ? lane*4+2 : hb.y ? lane*4+1 : (hb.x ? lane*4 : -1);
    #pragma unroll
    for (int off = 1; off < 64; off <<= 1) md = max(md, __shfl_xor(md, off, 64));
    float m = __half2float(__ushort_as_half((unsigned short)ou16_inv((unsigned)md * 256u + 255u)));
    if (lane == 0) {
      uint4 dk = { (p0 >> 16) | ((p1 >> 16) << 8) | ((p2 >> 16) << 16),
                   (p0 & 0xFFFFu) | ((p1 & 0xFFFFu) << 16),
                   (p2 & 0xFFFFu),
                   __float_as_uint(m) };
      *(uint4*)(dkbuf + q * 16) = dk;
    }
  }
  __syncthreads();

  // ===== count2: register pass, restricted histograms for row lx (packed D0|D1, D2) =====
  uint4 dk = *(const uint4*)(dkbuf + lx * 16);
  const unsigned D0 = dk.x & 255u, D1 = (dk.x >> 8) & 255u, D2 = (dk.x >> 16) & 255u;
  const unsigned k0r = dk.y & 0xFFFFu, k1r = dk.y >> 16, k2r = dk.z;
  const float m = __uint_as_float(dk.w);
  unsigned* h2r = h2 + lx * 512;
  #pragma unroll
  for (int i = 0; i < 32; ++i) {
    unsigned uu = sreg[i];
    #pragma unroll
    for (int hp = 0; hp < 2; ++hp) {
      unsigned bits = (uu >> (hp * 16)) & 0xFFFFu;
      unsigned ou = ou16_of(bits);
      unsigned hi = ou >> 8, lo = ou & 255u;
      unsigned add = (hi == D0 ? 1u : 0u) | (hi == D1 ? 0x10000u : 0u);
      if (add) atomicAdd(&h2r[lo * 2], add);
      if (hi == D2) atomicAdd(&h2r[lo * 2 + 1], 1u);
    }
  }
  __syncthreads();

  // ===== round 2: wave w selects T thresholds for rows 2w, 2w+1 =====
  #pragma unroll
  for (int rr = 0; rr < 2; ++rr) {
    int q = 2 * w + rr;
    const unsigned* hr = h2 + q * 512 + lane * 8;
    uint4 v0 = *(const uint4*)hr;
    uint4 v1 = *(const uint4*)(hr + 4);
    uint4 dkq = *(const uint4*)(dkbuf + q * 16);
    unsigned Dq0 = dkq.x & 255u, Dq1 = (dkq.x >> 8) & 255u, Dq2 = (dkq.x >> 16) & 255u;
    // D0 counts: low16 of packed words
    unsigned hx = v0.x & 0xFFFFu, hy = v0.z & 0xFFFFu, hz = v1.x & 0xFFFFu, hw_ = v1.z & 0xFFFFu;
    unsigned t0 = suffix64(hx + hy + hz + hw_, lane);
    unsigned T1o = (Dq0 << 8) | (pick_digit(t0, hx, hy, hz, hw_, dkq.y & 0xFFFFu, lane) >> 16);
    // D1 counts: high16
    hx = v0.x >> 16; hy = v0.z >> 16; hz = v1.x >> 16; hw_ = v1.z >> 16;
    unsigned t1 = suffix64(hx + hy + hz + hw_, lane);
    unsigned T2o = (Dq1 << 8) | (pick_digit(t1, hx, hy, hz, hw_, dkq.y >> 16, lane) >> 16);
    // D2 counts
    hx = v0.y; hy = v0.w; hz = v1.y; hw_ = v1.w;
    unsigned t2 = suffix64(hx + hy + hz + hw_, lane);
    unsigned T3o = (Dq2 << 8) | (pick_digit(t2, hx, hy, hz, hw_, dkq.z, lane) >> 16);
    if (lane == 0) {
      uint4 tm = {T1o, T2o, T3o, 0u};
      *(uint4*)(tmbuf + q * 16) = tm;
    }
  }
  __syncthreads();

  // ===== Z pass (register): e = exp(s-m) overwrites sreg; z1..z3 accumulate =====
  uint4 tm = *(const uint4*)(tmbuf + lx * 16);
  const unsigned T1o = tm.x, T2o = tm.y, T3o = tm.z;
  float z1 = 0.f, z2 = 0.f, z3 = 0.f;
  #pragma unroll
  for (int i = 0; i < 32; ++i) {
    unsigned uu = sreg[i];
    unsigned b0 = uu & 0xFFFFu, b1 = uu >> 16;
    float s0 = __half2float(__ushort_as_half((unsigned short)b0));
    float s1 = __half2float(__ushort_as_half((unsigned short)b1));
    float e0 = __expf(s0 - m), e1 = __expf(s1 - m);
    unsigned o0 = ou16_of(b0), o1 = ou16_of(b1);
    if (o0 >= T3o) z3 += e0;
    if (o0 >= T2o) z2 += e0;
    if (o0 >= T1o) z1 += e0;
    if (o1 >= T3o) z3 += e1;
    if (o1 >= T2o) z2 += e1;
    if (o1 >= T1o) z1 += e1;
    sreg[i] = pk2(e0, e1);
  }
  // reduce across the 4 lanes sharing lx within this wave
  z1 += __uint_as_float(shflx(__float_as_uint(z1), 16));
  z2 += __uint_as_float(shflx(__float_as_uint(z2), 16));
  z3 += __uint_as_float(shflx(__float_as_uint(z3), 16));
  z1 += __uint_as_float(shflx(__float_as_uint(z1), 32));
  z2 += __uint_as_float(shflx(__float_as_uint(z2), 32));
  z3 += __uint_as_float(shflx(__float_as_uint(z3), 32));
  if (g == 0) {
    float4 zv = {z1, z2, z3, 0.f};
    *(float4*)(zbuf + (lx * 8 + w) * 16) = zv;
  }
  __syncthreads();

  // ===== weight coefficients (read scratch BEFORE weights overwrite it) =====
  float zs1 = 0.f, zs2 = 0.f, zs3 = 0.f;
  #pragma unroll
  for (int ww = 0; ww < 8; ++ww) {
    float4 zv = *(const float4*)(zbuf + (lx * 8 + ww) * 16);
    zs1 += zv.x; zs2 += zv.y; zs3 += zv.z;
  }
  float A3 = aw2 / zs3;
  float A2 = aw1 / zs2 + A3;
  float A1 = aw0 / zs1 + A2;
  A1 *= WSC; A2 *= WSC; A3 *= WSC;
  float T1f = __half2float(__ushort_as_half((unsigned short)ou16_inv(T1o)));
  float T2f = __half2float(__ushort_as_half((unsigned short)ou16_inv(T2o)));
  float T3f = __half2float(__ushort_as_half((unsigned short)ou16_inv(T3o)));
  unsigned e1b = pk2(__expf(T1f - m), 0.f) & 0xFFFFu;
  unsigned e2b = pk2(__expf(T2f - m), 0.f) & 0xFFFFu;
  unsigned e3b = pk2(__expf(T3f - m), 0.f) & 0xFFFFu;
  __syncthreads();

  // ===== weight pass (register -> LDS weights, single write) =====
  const unsigned swl = (((unsigned)(lx & 7)) << 4) | (((unsigned)(lx & 8)) << 3);
  #pragma unroll
  for (int t = 0; t < 16; ++t) {
    int s0 = (t * 8 + w) * 16;
    unsigned u0 = sreg[2*t], u1 = sreg[2*t+1];
    unsigned b0 = u0 & 0xFFFFu, b1 = u0 >> 16;
    unsigned b2 = u1 & 0xFFFFu, b3 = u1 >> 16;
    float e0 = __half2float(__ushort_as_half((unsigned short)b0));
    float e1 = __half2float(__ushort_as_half((unsigned short)b1));
    float e2 = __half2float(__ushort_as_half((unsigned short)b2));
    float e3 = __half2float(__ushort_as_half((unsigned short)b3));
    float c0 = (b0 >= e1b) ? A1 : (b0 >= e2b) ? A2 : (b0 >= e3b) ? A3 : 0.f;
    float c1 = (b1 >= e1b) ? A1 : (b1 >= e2b) ? A2 : (b1 >= e3b) ? A3 : 0.f;
    float c2 = (b2 >= e1b) ? A1 : (b2 >= e2b) ? A2 : (b2 >= e3b) ? A3 : 0.f;
    float c3 = (b3 >= e1b) ? A1 : (b3 >= e2b) ? A2 : (b3 >= e3b) ? A3 : 0.f;
    uint2 wv = { pk2(e0 * c0, e1 * c1), pk2(e2 * c2, e3 * c3) };
    *(uint2*)(lds + lx * 4096 + (((unsigned)(s0 * 2 + g * 8)) ^ swl)) = wv;
  }
  __syncthreads();

  // ===== PV: out^T[d][q] = sum_s Vt[d][s] * w[q][s]; 8 waves = 4 d-tiles x 2 s-halves =====
  f32x4 oacc = {0.f, 0.f, 0.f, 0.f};
  const int dt = (w >> 1) * 16;
  const int sh = w & 1;
  const unsigned short* vp = Vtb + (size_t)(dt + lx) * 2048 + sh * 1024 + g * 8;
  const char* bp = lds + lx * 4096;

  #pragma unroll 8
  for (int kc = 0; kc < 32; ++kc) {
    f16x8 av = *(const f16x8*)(vp + kc * 32);
    unsigned sb = (unsigned)((sh * 1024 + kc * 32 + g * 8) * 2);
    f16x8 bv = *(const f16x8*)(bp + (sb ^ swl));
    oacc = __builtin_amdgcn_mfma_f32_16x16x32_f16(av, bv, oacc, 0, 0, 0);
  }

  float* pbuf = (float*)hist1;   // 8 waves x 256 floats = 8KB (hist1 dead)
  *(f32x4*)(pbuf + w * 256 + lx * 16 + g * 4) = oacc;
  __syncthreads();
  if (w < 4) {
    const float* pa = pbuf + (2 * w) * 256 + lx * 16 + g * 4;
    float4 ra = *(const float4*)pa;
    float4 rb = *(const float4*)(pa + 256);
    float* op = Out + (((size_t)b * 2048 + l0 + lx) * 8 + hh) * 64 + w * 16 + g * 4;
    float4 ov = { (ra.x + rb.x) * (1.f/WSC), (ra.y + rb.y) * (1.f/WSC),
                  (ra.z + rb.z) * (1.f/WSC), (ra.w + rb.w) * (1.f/WSC) };
    *(float4*)op = ov;
  }
}

extern "C" void kernel_launch(void* const* d_in, const int* in_sizes, int n_in,
                              void* d_out, int out_size, void* d_ws, size_t ws_size,
                              hipStream_t stream) {
  (void)in_sizes; (void)n_in; (void)out_size; (void)ws_size;
  const float* Q  = (const float*)d_in[0];
  const float* K  = (const float*)d_in[1];
  const float* V  = (const float*)d_in[2];
  const float* AW = (const float*)d_in[3];
  unsigned short* Kh = (unsigned short*)d_ws;                    // 8.4 MB
  unsigned short* Vt = (unsigned short*)((char*)d_ws + 8388608); // 8.4 MB
  prep_k<<<dim3(2048), dim3(256), 0, stream>>>(K, Kh);
  prep_v<<<dim3(512),  dim3(256), 0, stream>>>(V, Vt);
  nma_kernel<<<dim3(4096), dim3(512), 0, stream>>>(Q, Kh, Vt, AW, (float*)d_out);
}